// Round 1
// baseline (162.240 us; speedup 1.0000x reference)
//
#include <hip/hip_runtime.h>

// DenseWarp: out[b,c,y,x] = bilinear(frame[b,c], qy, qx)
//   qy = clip(y - flow[b,0,y,x], 0, H-1), qx = clip(x - flow[b,1,y,x], 0, W-1)
// fp32 in/out. B=4, C=4, H=1080, W=1920.

#define BB 4
#define CC 4
#define HH 1080
#define WW 1920
#define HW (HH * WW)
#define WQ (WW / 4)   // 480 float4-quads per row

__global__ __launch_bounds__(256) void dense_warp_kernel(
    const float* __restrict__ frame,
    const float* __restrict__ flow,
    float* __restrict__ out)
{
    const int tid = blockIdx.x * blockDim.x + threadIdx.x;
    const int nquad = BB * HH * WQ;
    if (tid >= nquad) return;

    const int xq   = tid % WQ;
    const int rest = tid / WQ;
    const int y    = rest % HH;
    const int b    = rest / HH;
    const int xpix = xq * 4;

    // Coalesced float4 flow loads (flow_y plane then flow_x plane)
    const float4 fy4 = *reinterpret_cast<const float4*>(
        flow + (size_t)(b * 2 + 0) * HW + (size_t)y * WW + xpix);
    const float4 fx4 = *reinterpret_cast<const float4*>(
        flow + (size_t)(b * 2 + 1) * HW + (size_t)y * WW + xpix);

    const float fy[4] = {fy4.x, fy4.y, fy4.z, fy4.w};
    const float fx[4] = {fx4.x, fx4.y, fx4.z, fx4.w};

    int   base00[4], base01[4], base10[4], base11[4];
    float wy[4], wx[4];

#pragma unroll
    for (int i = 0; i < 4; ++i) {
        // clip(y - flow_y, 0, H-1) / clip(x - flow_x, 0, W-1), same order as ref
        float qy = fminf(fmaxf((float)y - fy[i], 0.0f), (float)(HH - 1));
        float qx = fminf(fmaxf((float)(xpix + i) - fx[i], 0.0f), (float)(WW - 1));
        float y0f = floorf(qy);
        float x0f = floorf(qx);
        wy[i] = qy - y0f;
        wx[i] = qx - x0f;
        int y0 = (int)y0f;
        int x0 = (int)x0f;
        int y1 = min(y0 + 1, HH - 1);
        int x1 = min(x0 + 1, WW - 1);
        base00[i] = y0 * WW + x0;
        base01[i] = y0 * WW + x1;
        base10[i] = y1 * WW + x0;
        base11[i] = y1 * WW + x1;
    }

    // Reuse indices/weights across all 4 channels
#pragma unroll
    for (int c = 0; c < CC; ++c) {
        const float* fp = frame + (size_t)(b * CC + c) * HW;
        float4 o;
        float ov[4];
#pragma unroll
        for (int i = 0; i < 4; ++i) {
            float tl = fp[base00[i]];
            float tr = fp[base01[i]];
            float bl = fp[base10[i]];
            float br = fp[base11[i]];
            float top = tl * (1.0f - wx[i]) + tr * wx[i];
            float bot = bl * (1.0f - wx[i]) + br * wx[i];
            ov[i] = top * (1.0f - wy[i]) + bot * wy[i];
        }
        o.x = ov[0]; o.y = ov[1]; o.z = ov[2]; o.w = ov[3];
        *reinterpret_cast<float4*>(
            out + (size_t)(b * CC + c) * HW + (size_t)y * WW + xpix) = o;
    }
}

extern "C" void kernel_launch(void* const* d_in, const int* in_sizes, int n_in,
                              void* d_out, int out_size, void* d_ws, size_t ws_size,
                              hipStream_t stream)
{
    const float* frame = (const float*)d_in[0];
    const float* flow  = (const float*)d_in[1];
    float* out = (float*)d_out;

    const int nquad = BB * HH * WQ;               // 2,073,600 threads
    const int block = 256;
    const int grid  = (nquad + block - 1) / block; // 8100 blocks

    dense_warp_kernel<<<grid, block, 0, stream>>>(frame, flow, out);
}

// Round 2
// 123.278 us; speedup vs baseline: 1.3161x; 1.3161x over previous
//
#include <hip/hip_runtime.h>

// DenseWarp: out[b,c,y,x] = bilinear(frame[b,c], qy, qx)
//   qy = clip(y - flow[b,0,y,x], 0, H-1), qx = clip(x - flow[b,1,y,x], 0, W-1)
// fp32 in/out. B=4, C=4, H=1080, W=1920.
//
// R2: pixel-per-thread (gather lanes adjacent -> coalesced), bijective
// XCD band swizzle (frame row reuse stays in one L2), non-temporal stores.

#define BB 4
#define CC 4
#define HH 1080
#define WW 1920
#define HW (HH * WW)
#define NPIX (BB * HH * WW)      // 16,588,800
#define NBLK (NPIX / 256)        // 64,800  (divisible by 8)

__global__ __launch_bounds__(256) void dense_warp_kernel(
    const float* __restrict__ frame,
    const float* __restrict__ flow,
    float* __restrict__ out)
{
    // Bijective XCD band swizzle: hw block n -> XCD n&7 -> band-local n>>3.
    // Each XCD owns a contiguous 1/8 of the (b,y) row space, so the ~12-row
    // frame reuse window stays inside one XCD's L2.
    const int n   = blockIdx.x;
    const int blk = (n & 7) * (NBLK >> 3) + (n >> 3);

    const int p = blk * 256 + threadIdx.x;   // global pixel index
    const int x = p % WW;
    const int t = p / WW;
    const int y = t % HH;
    const int b = t / HH;

    const size_t rowoff = (size_t)y * WW + x;
    const float fy = flow[(size_t)(b * 2 + 0) * HW + rowoff];
    const float fx = flow[(size_t)(b * 2 + 1) * HW + rowoff];

    // clip(y - flow_y, 0, H-1) / clip(x - flow_x, 0, W-1) — same order as ref
    const float qy = fminf(fmaxf((float)y - fy, 0.0f), (float)(HH - 1));
    const float qx = fminf(fmaxf((float)x - fx, 0.0f), (float)(WW - 1));
    const float y0f = floorf(qy);
    const float x0f = floorf(qx);
    const float wy = qy - y0f;
    const float wx = qx - x0f;
    const int y0 = (int)y0f;
    const int x0 = (int)x0f;
    const int y1 = min(y0 + 1, HH - 1);
    const int x1 = min(x0 + 1, WW - 1);

    const int i00 = y0 * WW + x0;
    const int i01 = y0 * WW + x1;
    const int i10 = y1 * WW + x0;
    const int i11 = y1 * WW + x1;

    const float omwx = 1.0f - wx;
    const float omwy = 1.0f - wy;

#pragma unroll
    for (int c = 0; c < CC; ++c) {
        const float* fp = frame + (size_t)(b * CC + c) * HW;
        const float tl = fp[i00];
        const float tr = fp[i01];
        const float bl = fp[i10];
        const float br = fp[i11];
        const float top = tl * omwx + tr * wx;
        const float bot = bl * omwx + br * wx;
        const float v   = top * omwy + bot * wy;
        __builtin_nontemporal_store(v, out + (size_t)(b * CC + c) * HW + rowoff);
    }
}

extern "C" void kernel_launch(void* const* d_in, const int* in_sizes, int n_in,
                              void* d_out, int out_size, void* d_ws, size_t ws_size,
                              hipStream_t stream)
{
    const float* frame = (const float*)d_in[0];
    const float* flow  = (const float*)d_in[1];
    float* out = (float*)d_out;

    dense_warp_kernel<<<NBLK, 256, 0, stream>>>(frame, flow, out);
}

// Round 3
// 76.645 us; speedup vs baseline: 2.1168x; 1.6084x over previous
//
#include <hip/hip_runtime.h>

// DenseWarp: out[b,c,y,x] = bilinear(frame[b,c], qy, qx)
//   qy = clip(y - flow[b,0,y,x], 0, H-1), qx = clip(x - flow[b,1,y,x], 0, W-1)
// fp32 in/out. B=4, C=4, H=1080, W=1920.
//
// R3: merge (tl,tr) and (bl,br) into single 8B gathers (x1 = x0+1 in the
// same dwordx2) -> halves L1/TCP line-lookups, which R2 showed to be the
// ceiling (1.14 lookups/cycle/CU). Right-edge handled by loading at W-2
// and forcing wx=1 (identical result to ref's clamp). Keeps pixel-per-
// thread mapping, XCD band swizzle, non-temporal stores.

#define BB 4
#define CC 4
#define HH 1080
#define WW 1920
#define HW (HH * WW)
#define NPIX (BB * HH * WW)      // 16,588,800
#define NBLK (NPIX / 256)        // 64,800  (divisible by 8)

typedef float f32x2 __attribute__((ext_vector_type(2), aligned(4)));

__global__ __launch_bounds__(256) void dense_warp_kernel(
    const float* __restrict__ frame,
    const float* __restrict__ flow,
    float* __restrict__ out)
{
    // Bijective XCD band swizzle: hw block n -> XCD n&7 -> band-local n>>3.
    const int n   = blockIdx.x;
    const int blk = (n & 7) * (NBLK >> 3) + (n >> 3);

    const int p = blk * 256 + threadIdx.x;   // global pixel index
    const int x = p % WW;
    const int t = p / WW;
    const int y = t % HH;
    const int b = t / HH;

    const size_t rowoff = (size_t)y * WW + x;
    const float fy = flow[(size_t)(b * 2 + 0) * HW + rowoff];
    const float fx = flow[(size_t)(b * 2 + 1) * HW + rowoff];

    // clip(y - flow_y, 0, H-1) / clip(x - flow_x, 0, W-1) — same order as ref
    const float qy = fminf(fmaxf((float)y - fy, 0.0f), (float)(HH - 1));
    const float qx = fminf(fmaxf((float)x - fx, 0.0f), (float)(WW - 1));
    const float y0f = floorf(qy);
    const float x0f = floorf(qx);
    const float wy = qy - y0f;
    float       wx = qx - x0f;
    const int y0 = (int)y0f;
    const int x0 = (int)x0f;
    const int y1 = min(y0 + 1, HH - 1);

    // Right-edge: x0 == W-1 implies qx == W-1 and wx == 0; ref yields
    // top = frame[W-1]. Load the pair at W-2 and set wx = 1 -> identical.
    const bool edge = (x0 > WW - 2);
    const int  xb   = edge ? (WW - 2) : x0;
    if (edge) wx = 1.0f;

    const int i0 = y0 * WW + xb;   // top pair base
    const int i1 = y1 * WW + xb;   // bottom pair base

    const float omwx = 1.0f - wx;
    const float omwy = 1.0f - wy;

#pragma unroll
    for (int c = 0; c < CC; ++c) {
        const float* fp = frame + (size_t)(b * CC + c) * HW;
        const f32x2 t2 = *reinterpret_cast<const f32x2*>(fp + i0);
        const f32x2 b2 = *reinterpret_cast<const f32x2*>(fp + i1);
        const float top = t2.x * omwx + t2.y * wx;
        const float bot = b2.x * omwx + b2.y * wx;
        const float v   = top * omwy + bot * wy;
        __builtin_nontemporal_store(v, out + (size_t)(b * CC + c) * HW + rowoff);
    }
}

extern "C" void kernel_launch(void* const* d_in, const int* in_sizes, int n_in,
                              void* d_out, int out_size, void* d_ws, size_t ws_size,
                              hipStream_t stream)
{
    const float* frame = (const float*)d_in[0];
    const float* flow  = (const float*)d_in[1];
    float* out = (float*)d_out;

    dense_warp_kernel<<<NBLK, 256, 0, stream>>>(frame, flow, out);
}